// Round 7
// baseline (454.593 us; speedup 1.0000x reference)
//
#include <hip/hip_runtime.h>
#include <math.h>

#define DIN  128
#define HC   128
#define NEG  0.2f

typedef __attribute__((ext_vector_type(8))) short bf16x8;
typedef __attribute__((ext_vector_type(4))) float f32x4;

__device__ __forceinline__ unsigned short f2bf_rne(float x) {
    unsigned u = __float_as_uint(x);
    unsigned r = u + 0x7FFFu + ((u >> 16) & 1u);
    return (unsigned short)(r >> 16);
}
__device__ __forceinline__ float bf2f(unsigned short h) {
    return __uint_as_float(((unsigned)h) << 16);
}

// ---------------------------------------------------------------------------
// CSR build
// ---------------------------------------------------------------------------
__global__ void hist_kernel(const int* __restrict__ ei, int E, int N,
                            int* __restrict__ counts) {
    int i = blockIdx.x * blockDim.x + threadIdx.x;
    int Etot = E + N;
    if (i >= Etot) return;
    int dst = (i < E) ? ei[E + i] : (i - E);
    if (dst < 0 || dst >= N) return;
    atomicAdd(&counts[dst], 1);
}

// single-block scan, 4 elems/thread (int4)
__global__ void scan_kernel(const int* __restrict__ counts,
                            int* __restrict__ rowptr,
                            int* __restrict__ cursor, int n) {
    __shared__ int wsum[16];
    int tid  = threadIdx.x;          // 1024 threads
    int lane = tid & 63, wid = tid >> 6;
    int running = 0;
    for (int base = 0; base < n; base += 4096) {
        int i = base + tid * 4;
        int4 v = make_int4(0, 0, 0, 0);
        if (i < n) v = *(const int4*)&counts[i];   // n % 4 == 0
        int ssum = v.x + v.y + v.z + v.w;
        int x = ssum;
        #pragma unroll
        for (int off = 1; off < 64; off <<= 1) {
            int y = __shfl_up(x, off, 64);
            if (lane >= off) x += y;
        }
        if (lane == 63) wsum[wid] = x;
        __syncthreads();
        if (tid < 16) {
            int w = wsum[tid];
            #pragma unroll
            for (int off = 1; off < 16; off <<= 1) {
                int y = __shfl_up(w, off, 64);
                if (tid >= off) w += y;
            }
            wsum[tid] = w;
        }
        __syncthreads();
        int excl = running + (wid ? wsum[wid - 1] : 0) + (x - ssum);
        if (i < n) {
            int4 r;
            r.x = excl;
            r.y = r.x + v.x;
            r.z = r.y + v.y;
            r.w = r.z + v.z;
            *(int4*)&rowptr[i] = r;
            *(int4*)&cursor[i] = r;
        }
        running += wsum[15];
        __syncthreads();
    }
    if (tid == 0) rowptr[n] = running;
}

__global__ void scatter_kernel(const int* __restrict__ ei, int E, int N,
                               int* __restrict__ cursor,
                               int* __restrict__ esrc) {
    int i = blockIdx.x * blockDim.x + threadIdx.x;
    int Etot = E + N;
    if (i >= Etot) return;
    int src = (i < E) ? ei[i]     : (i - E);
    int dst = (i < E) ? ei[E + i] : (i - E);
    if (dst < 0 || dst >= N || src < 0 || src >= N) return;
    int pos = atomicAdd(&cursor[dst], 1);
    esrc[pos] = src;
}

// ---------------------------------------------------------------------------
// W prep: split each 128x128 W into bf16 hi/lo, packed in MFMA B-fragment
// order: slot (kb,nf,lane,j) = W[kb*32 + (lane>>4)*8 + j][nf*16 + (lane&15)].
// ---------------------------------------------------------------------------
__global__ __launch_bounds__(256) void prep_w(
        const float* __restrict__ W1l, const float* __restrict__ W1r,
        const float* __restrict__ W2l, const float* __restrict__ W2r,
        const float* __restrict__ W3l, const float* __restrict__ W3r,
        unsigned short* __restrict__ hi, unsigned short* __restrict__ lo) {
    int m = blockIdx.y;
    const float* W = (m == 0) ? W1l : (m == 1) ? W1r : (m == 2) ? W2l
                   : (m == 3) ? W2r : (m == 4) ? W3l : W3r;
    int t = blockIdx.x * 256 + threadIdx.x;    // 0..2047 (grid.x = 8)
    int kb = t >> 9, nf = (t >> 6) & 7, l = t & 63;
    int col = nf * 16 + (l & 15);
    int k0  = kb * 32 + (l >> 4) * 8;
    size_t ob = ((size_t)m * 2048 + t) * 8;
    #pragma unroll
    for (int j = 0; j < 8; ++j) {
        float v = W[(size_t)(k0 + j) * 128 + col];
        unsigned short h = f2bf_rne(v);
        hi[ob + j] = h;
        lo[ob + j] = f2bf_rne(v - bf2f(h));
    }
}

// ---------------------------------------------------------------------------
// MFMA GEMM (split-bf16, 3 terms): Out = X@W + b, X:[n,128] fp32, W packed.
// ---------------------------------------------------------------------------
__global__ __launch_bounds__(256) void gemm_mfma(
        const float* __restrict__ X,
        const unsigned short* __restrict__ Whi,
        const unsigned short* __restrict__ Wlo, int matbase,
        const float* __restrict__ bl, const float* __restrict__ br,
        float* __restrict__ xl, float* __restrict__ xr, int nrows) {
    const float* bias = blockIdx.y ? br : bl;
    float*       Out  = blockIdx.y ? xr : xl;
    const unsigned short* hp = Whi + ((size_t)(matbase + blockIdx.y) * 16384);
    const unsigned short* lp = Wlo + ((size_t)(matbase + blockIdx.y) * 16384);

    int w   = threadIdx.x >> 6;
    int l   = threadIdx.x & 63;
    int m15 = l & 15, g = l >> 4;
    int rowbase = blockIdx.x * 64 + w * 16;

    f32x4 acc[8];
    #pragma unroll
    for (int nf = 0; nf < 8; ++nf) acc[nf] = (f32x4){0.f, 0.f, 0.f, 0.f};

    #pragma unroll
    for (int kb = 0; kb < 4; ++kb) {
        int arow = rowbase + m15;
        float4 x0 = make_float4(0.f, 0.f, 0.f, 0.f), x1 = x0;
        if (arow < nrows) {
            const float* xp = &X[(size_t)arow * 128 + kb * 32 + g * 8];
            x0 = *(const float4*)xp;
            x1 = *(const float4*)(xp + 4);
        }
        float xv[8] = {x0.x, x0.y, x0.z, x0.w, x1.x, x1.y, x1.z, x1.w};
        bf16x8 ahi, alo;
        #pragma unroll
        for (int j = 0; j < 8; ++j) {
            unsigned short h = f2bf_rne(xv[j]);
            ahi[j] = (short)h;
            alo[j] = (short)f2bf_rne(xv[j] - bf2f(h));
        }
        #pragma unroll
        for (int nf = 0; nf < 8; ++nf) {
            size_t off = (((size_t)kb * 8 + nf) * 64 + l) * 8;
            bf16x8 bhi = *(const bf16x8*)&hp[off];
            bf16x8 blo = *(const bf16x8*)&lp[off];
            acc[nf] = __builtin_amdgcn_mfma_f32_16x16x32_bf16(ahi, bhi, acc[nf], 0, 0, 0);
            acc[nf] = __builtin_amdgcn_mfma_f32_16x16x32_bf16(ahi, blo, acc[nf], 0, 0, 0);
            acc[nf] = __builtin_amdgcn_mfma_f32_16x16x32_bf16(alo, bhi, acc[nf], 0, 0, 0);
        }
    }

    // C/D layout: col = lane&15, row = (lane>>4)*4 + reg
    #pragma unroll
    for (int nf = 0; nf < 8; ++nf) {
        int col = nf * 16 + m15;
        float b = bias[col];
        #pragma unroll
        for (int r = 0; r < 4; ++r) {
            int row = rowbase + g * 4 + r;
            if (row < nrows)
                Out[(size_t)row * 128 + col] = acc[nf][r] + b;
        }
    }
}

// ---------------------------------------------------------------------------
// Fused GATv2 aggregation — NO-MAX softmax (shift-invariant; scores O(+-10),
// exp clamped at +80 for overflow insurance). No running max -> no serial
// rescale chain; per-edge update is p=exp(t); s+=p; acc+=p*a (independent
// across edges). 8 edges in flight per wave (4 groups x 16 lanes x 2 edges).
// Branch-free B edge: sB falls back to sA, tB killed with -1e30 (exp -> 0).
// Optional fused output projection (layer 3).
// ---------------------------------------------------------------------------
__device__ __forceinline__ float dsel(float4 a, float4 x, float4 tp, float4 tn) {
    float r, v;
    v = a.x + x.x; r  = v * (v > 0.f ? tp.x : tn.x);
    v = a.y + x.y; r += v * (v > 0.f ? tp.y : tn.y);
    v = a.z + x.z; r += v * (v > 0.f ? tp.z : tn.z);
    v = a.w + x.w; r += v * (v > 0.f ? tp.w : tn.w);
    return r;
}

__global__ __launch_bounds__(256) void gat_aggregate(
        const float* __restrict__ xl, const float* __restrict__ xr,
        const int* __restrict__ rowptr, const int* __restrict__ esrc,
        const float* __restrict__ att, const float* __restrict__ bias,
        float* __restrict__ hout, int n, int do_relu,
        const float* __restrict__ Wout, const float* __restrict__ bout,
        float* __restrict__ out4) {
    int node = (int)((blockIdx.x * blockDim.x + threadIdx.x) >> 6);
    int lane = threadIdx.x & 63;
    if (node >= n) return;
    int g  = lane >> 4;
    int gl = lane & 15;
    int c0 = gl * 4;

    const float* xrp = &xr[(size_t)node * 128];
    float4 xr0 = *(const float4*)&xrp[c0];
    float4 xr1 = *(const float4*)&xrp[64 + c0];
    float4 atp0 = *(const float4*)&att[c0];
    float4 atp1 = *(const float4*)&att[64 + c0];
    float4 atn0 = make_float4(NEG * atp0.x, NEG * atp0.y, NEG * atp0.z, NEG * atp0.w);
    float4 atn1 = make_float4(NEG * atp1.x, NEG * atp1.y, NEG * atp1.z, NEG * atp1.w);

    float s0 = 0.f, s1 = 0.f;
    float4 acc0 = make_float4(0.f, 0.f, 0.f, 0.f);
    float4 acc1 = make_float4(0.f, 0.f, 0.f, 0.f);

    int pbeg = rowptr[node], pend = rowptr[node + 1];
    for (int p = pbeg + g; p < pend; p += 8) {
        int  sA   = esrc[p];
        bool hasB = (p + 4 < pend);              // uniform within 16-lane group
        int  sB   = hasB ? esrc[p + 4] : sA;     // safe fallback, branch-free loads
        const float* xpA = &xl[(size_t)sA * 128];
        const float* xpB = &xl[(size_t)sB * 128];
        float4 a0A = *(const float4*)&xpA[c0];
        float4 a1A = *(const float4*)&xpA[64 + c0];
        float4 a0B = *(const float4*)&xpB[c0];
        float4 a1B = *(const float4*)&xpB[64 + c0];

        float tA0 = dsel(a0A, xr0, atp0, atn0), tA1 = dsel(a1A, xr1, atp1, atn1);
        float tB0 = dsel(a0B, xr0, atp0, atn0), tB1 = dsel(a1B, xr1, atp1, atn1);
        #pragma unroll
        for (int off = 1; off < 16; off <<= 1) {
            tA0 += __shfl_xor(tA0, off, 64);
            tA1 += __shfl_xor(tA1, off, 64);
            tB0 += __shfl_xor(tB0, off, 64);
            tB1 += __shfl_xor(tB1, off, 64);
        }
        tB0 = hasB ? tB0 : -1e30f;
        tB1 = hasB ? tB1 : -1e30f;

        float pA0 = __expf(fminf(tA0, 80.f));
        float pA1 = __expf(fminf(tA1, 80.f));
        float pB0 = __expf(fminf(tB0, 80.f));
        float pB1 = __expf(fminf(tB1, 80.f));

        s0 += pA0 + pB0;
        s1 += pA1 + pB1;
        acc0.x += pA0 * a0A.x + pB0 * a0B.x;  acc0.y += pA0 * a0A.y + pB0 * a0B.y;
        acc0.z += pA0 * a0A.z + pB0 * a0B.z;  acc0.w += pA0 * a0A.w + pB0 * a0B.w;
        acc1.x += pA1 * a1A.x + pB1 * a1B.x;  acc1.y += pA1 * a1A.y + pB1 * a1B.y;
        acc1.z += pA1 * a1A.z + pB1 * a1B.z;  acc1.w += pA1 * a1A.w + pB1 * a1B.w;
    }

    // plain butterfly sum across the 4 groups (xor 16 then 32)
    #pragma unroll
    for (int off = 16; off <= 32; off <<= 1) {
        s0 += __shfl_xor(s0, off, 64);
        s1 += __shfl_xor(s1, off, 64);
        acc0.x += __shfl_xor(acc0.x, off, 64); acc0.y += __shfl_xor(acc0.y, off, 64);
        acc0.z += __shfl_xor(acc0.z, off, 64); acc0.w += __shfl_xor(acc0.w, off, 64);
        acc1.x += __shfl_xor(acc1.x, off, 64); acc1.y += __shfl_xor(acc1.y, off, 64);
        acc1.z += __shfl_xor(acc1.z, off, 64); acc1.w += __shfl_xor(acc1.w, off, 64);
    }

    float inv0 = 1.f / s0, inv1 = 1.f / s1;

    if (out4) {
        // fused output projection: all lanes hold the full merged state.
        float o0[4], o1[4];
        float a0v[4] = {acc0.x, acc0.y, acc0.z, acc0.w};
        float a1v[4] = {acc1.x, acc1.y, acc1.z, acc1.w};
        #pragma unroll
        for (int i = 0; i < 4; ++i) {
            o0[i] = a0v[i] * inv0 + bias[c0 + i];
            o1[i] = a1v[i] * inv1 + bias[64 + c0 + i];
            if (do_relu) { o0[i] = fmaxf(o0[i], 0.f); o1[i] = fmaxf(o1[i], 0.f); }
        }
        float p0 = 0.f, p1 = 0.f, p2 = 0.f, p3 = 0.f;
        #pragma unroll
        for (int i = 0; i < 4; ++i) {
            float4 w = *(const float4*)&Wout[(c0 + i) * 4];
            p0 += o0[i] * w.x; p1 += o0[i] * w.y; p2 += o0[i] * w.z; p3 += o0[i] * w.w;
        }
        #pragma unroll
        for (int i = 0; i < 4; ++i) {
            float4 w = *(const float4*)&Wout[(64 + c0 + i) * 4];
            p0 += o1[i] * w.x; p1 += o1[i] * w.y; p2 += o1[i] * w.z; p3 += o1[i] * w.w;
        }
        #pragma unroll
        for (int off = 1; off < 16; off <<= 1) {
            p0 += __shfl_xor(p0, off, 64);
            p1 += __shfl_xor(p1, off, 64);
            p2 += __shfl_xor(p2, off, 64);
            p3 += __shfl_xor(p3, off, 64);
        }
        if (lane == 0) {
            float4 o = make_float4(p0 + bout[0], p1 + bout[1],
                                   p2 + bout[2], p3 + bout[3]);
            *(float4*)&out4[(size_t)node * 4] = o;
        }
        return;
    }

    if (g == 0) {
        float4 vb = *(const float4*)&bias[c0];
        float4 o = make_float4(acc0.x * inv0 + vb.x, acc0.y * inv0 + vb.y,
                               acc0.z * inv0 + vb.z, acc0.w * inv0 + vb.w);
        if (do_relu) {
            o.x = fmaxf(o.x, 0.f); o.y = fmaxf(o.y, 0.f);
            o.z = fmaxf(o.z, 0.f); o.w = fmaxf(o.w, 0.f);
        }
        *(float4*)&hout[(size_t)node * 128 + c0] = o;
    } else if (g == 1) {
        float4 vb = *(const float4*)&bias[64 + c0];
        float4 o = make_float4(acc1.x * inv1 + vb.x, acc1.y * inv1 + vb.y,
                               acc1.z * inv1 + vb.z, acc1.w * inv1 + vb.w);
        if (do_relu) {
            o.x = fmaxf(o.x, 0.f); o.y = fmaxf(o.y, 0.f);
            o.z = fmaxf(o.z, 0.f); o.w = fmaxf(o.w, 0.f);
        }
        *(float4*)&hout[(size_t)node * 128 + 64 + c0] = o;
    }
}

// ---------------------------------------------------------------------------
extern "C" void kernel_launch(void* const* d_in, const int* in_sizes, int n_in,
                              void* d_out, int out_size, void* d_ws,
                              size_t ws_size, hipStream_t stream) {
    // setup_inputs order:
    //  0:x 1:edge_index 2:W1l 3:b1l 4:W1r 5:b1r 6:att1 7:bias1
    //  8:W2l 9:b2l 10:W2r 11:b2r 12:att2 13:bias2
    // 14:W3l 15:b3l 16:W3r 17:b3r 18:att3 19:bias3 20:Wout 21:bout
    const float* x    = (const float*)d_in[0];
    const int*   ei   = (const int*)  d_in[1];
    const float* W1l  = (const float*)d_in[2];
    const float* b1l  = (const float*)d_in[3];
    const float* W1r  = (const float*)d_in[4];
    const float* b1r  = (const float*)d_in[5];
    const float* att1 = (const float*)d_in[6];
    const float* bias1= (const float*)d_in[7];
    const float* W2l  = (const float*)d_in[8];
    const float* b2l  = (const float*)d_in[9];
    const float* W2r  = (const float*)d_in[10];
    const float* b2r  = (const float*)d_in[11];
    const float* att2 = (const float*)d_in[12];
    const float* bias2= (const float*)d_in[13];
    const float* W3l  = (const float*)d_in[14];
    const float* b3l  = (const float*)d_in[15];
    const float* W3r  = (const float*)d_in[16];
    const float* b3r  = (const float*)d_in[17];
    const float* att3 = (const float*)d_in[18];
    const float* bias3= (const float*)d_in[19];
    const float* Wout = (const float*)d_in[20];
    const float* bout = (const float*)d_in[21];

    int N    = in_sizes[0] / DIN;
    int E    = in_sizes[1] / 2;
    int Etot = E + N;

    float* h      = (float*)d_ws;
    float* xl     = h  + (size_t)N * HC;
    float* xr     = xl + (size_t)N * HC;
    unsigned short* whi = (unsigned short*)(xr + (size_t)N * HC);
    unsigned short* wlo = whi + 6 * 16384;
    int*   esrc   = (int*)(wlo + 6 * 16384);
    int*   rowptr = esrc + Etot;
    int*   cursor = rowptr + (((N + 1) + 3) & ~3);   // keep cursor 16B-aligned
    int*   counts = cursor + N;

    hipMemsetAsync(counts, 0, (size_t)N * sizeof(int), stream);
    hist_kernel<<<(Etot + 255) / 256, 256, 0, stream>>>(ei, E, N, counts);
    scan_kernel<<<1, 1024, 0, stream>>>(counts, rowptr, cursor, N);
    scatter_kernel<<<(Etot + 255) / 256, 256, 0, stream>>>(ei, E, N, cursor, esrc);
    prep_w<<<dim3(8, 6), 256, 0, stream>>>(W1l, W1r, W2l, W2r, W3l, W3r, whi, wlo);

    dim3 gemm_grid((N + 63) / 64, 2);
    int  agg_grid = (N + 3) / 4;

    gemm_mfma<<<gemm_grid, 256, 0, stream>>>(x, whi, wlo, 0, b1l, b1r, xl, xr, N);
    gat_aggregate<<<agg_grid, 256, 0, stream>>>(xl, xr, rowptr, esrc, att1, bias1,
                                                h, N, 1, nullptr, nullptr, nullptr);
    gemm_mfma<<<gemm_grid, 256, 0, stream>>>(h, whi, wlo, 2, b2l, b2r, xl, xr, N);
    gat_aggregate<<<agg_grid, 256, 0, stream>>>(xl, xr, rowptr, esrc, att2, bias2,
                                                h, N, 1, nullptr, nullptr, nullptr);
    gemm_mfma<<<gemm_grid, 256, 0, stream>>>(h, whi, wlo, 4, b3l, b3r, xl, xr, N);
    // layer 3: fused relu + output projection, h never materialized
    gat_aggregate<<<agg_grid, 256, 0, stream>>>(xl, xr, rowptr, esrc, att3, bias3,
                                                nullptr, N, 1, Wout, bout,
                                                (float*)d_out);
}

// Round 8
// 419.271 us; speedup vs baseline: 1.0842x; 1.0842x over previous
//
#include <hip/hip_runtime.h>
#include <math.h>

#define DIN  128
#define HC   128
#define NEG  0.2f

typedef __attribute__((ext_vector_type(8))) short bf16x8;
typedef __attribute__((ext_vector_type(4))) float f32x4;

__device__ __forceinline__ unsigned short f2bf_rne(float x) {
    unsigned u = __float_as_uint(x);
    unsigned r = u + 0x7FFFu + ((u >> 16) & 1u);
    return (unsigned short)(r >> 16);
}
__device__ __forceinline__ float bf2f(unsigned short h) {
    return __uint_as_float(((unsigned)h) << 16);
}

// 16-lane (DPP-row) butterfly sum: xor1, xor2, xor7, xor15 — pure VALU.
// After the 4 steps every lane of the row holds the row total.
template <int CTRL>
__device__ __forceinline__ float dpp_xadd(float x) {
    int r = __builtin_amdgcn_update_dpp(0, __float_as_int(x), CTRL, 0xF, 0xF, true);
    return x + __int_as_float(r);
}
__device__ __forceinline__ float rowsum16(float x) {
    x = dpp_xadd<0xB1>(x);   // quad_perm [1,0,3,2]  : lane ^ 1
    x = dpp_xadd<0x4E>(x);   // quad_perm [2,3,0,1]  : lane ^ 2
    x = dpp_xadd<0x141>(x);  // row_half_mirror      : lane ^ 7
    x = dpp_xadd<0x140>(x);  // row_mirror           : lane ^ 15
    return x;
}

// ---------------------------------------------------------------------------
// CSR build
// ---------------------------------------------------------------------------
__global__ void hist_kernel(const int* __restrict__ ei, int E, int N,
                            int* __restrict__ counts) {
    int i = blockIdx.x * blockDim.x + threadIdx.x;
    int Etot = E + N;
    if (i >= Etot) return;
    int dst = (i < E) ? ei[E + i] : (i - E);
    if (dst < 0 || dst >= N) return;
    atomicAdd(&counts[dst], 1);
}

// single-block scan, 4 elems/thread (int4)
__global__ void scan_kernel(const int* __restrict__ counts,
                            int* __restrict__ rowptr,
                            int* __restrict__ cursor, int n) {
    __shared__ int wsum[16];
    int tid  = threadIdx.x;          // 1024 threads
    int lane = tid & 63, wid = tid >> 6;
    int running = 0;
    for (int base = 0; base < n; base += 4096) {
        int i = base + tid * 4;
        int4 v = make_int4(0, 0, 0, 0);
        if (i < n) v = *(const int4*)&counts[i];   // n % 4 == 0
        int ssum = v.x + v.y + v.z + v.w;
        int x = ssum;
        #pragma unroll
        for (int off = 1; off < 64; off <<= 1) {
            int y = __shfl_up(x, off, 64);
            if (lane >= off) x += y;
        }
        if (lane == 63) wsum[wid] = x;
        __syncthreads();
        if (tid < 16) {
            int w = wsum[tid];
            #pragma unroll
            for (int off = 1; off < 16; off <<= 1) {
                int y = __shfl_up(w, off, 64);
                if (tid >= off) w += y;
            }
            wsum[tid] = w;
        }
        __syncthreads();
        int excl = running + (wid ? wsum[wid - 1] : 0) + (x - ssum);
        if (i < n) {
            int4 r;
            r.x = excl;
            r.y = r.x + v.x;
            r.z = r.y + v.y;
            r.w = r.z + v.z;
            *(int4*)&rowptr[i] = r;
            *(int4*)&cursor[i] = r;
        }
        running += wsum[15];
        __syncthreads();
    }
    if (tid == 0) rowptr[n] = running;
}

__global__ void scatter_kernel(const int* __restrict__ ei, int E, int N,
                               int* __restrict__ cursor,
                               int* __restrict__ esrc) {
    int i = blockIdx.x * blockDim.x + threadIdx.x;
    int Etot = E + N;
    if (i >= Etot) return;
    int src = (i < E) ? ei[i]     : (i - E);
    int dst = (i < E) ? ei[E + i] : (i - E);
    if (dst < 0 || dst >= N || src < 0 || src >= N) return;
    int pos = atomicAdd(&cursor[dst], 1);
    esrc[pos] = src;
}

// ---------------------------------------------------------------------------
// W prep: split each 128x128 W into bf16 hi/lo, packed in MFMA B-fragment
// order: slot (kb,nf,lane,j) = W[kb*32 + (lane>>4)*8 + j][nf*16 + (lane&15)].
// ---------------------------------------------------------------------------
__global__ __launch_bounds__(256) void prep_w(
        const float* __restrict__ W1l, const float* __restrict__ W1r,
        const float* __restrict__ W2l, const float* __restrict__ W2r,
        const float* __restrict__ W3l, const float* __restrict__ W3r,
        unsigned short* __restrict__ hi, unsigned short* __restrict__ lo) {
    int m = blockIdx.y;
    const float* W = (m == 0) ? W1l : (m == 1) ? W1r : (m == 2) ? W2l
                   : (m == 3) ? W2r : (m == 4) ? W3l : W3r;
    int t = blockIdx.x * 256 + threadIdx.x;    // 0..2047 (grid.x = 8)
    int kb = t >> 9, nf = (t >> 6) & 7, l = t & 63;
    int col = nf * 16 + (l & 15);
    int k0  = kb * 32 + (l >> 4) * 8;
    size_t ob = ((size_t)m * 2048 + t) * 8;
    #pragma unroll
    for (int j = 0; j < 8; ++j) {
        float v = W[(size_t)(k0 + j) * 128 + col];
        unsigned short h = f2bf_rne(v);
        hi[ob + j] = h;
        lo[ob + j] = f2bf_rne(v - bf2f(h));
    }
}

// ---------------------------------------------------------------------------
// MFMA GEMM (split-bf16, 3 terms): Out = X@W + b, X:[n,128] fp32, W packed.
// ---------------------------------------------------------------------------
__global__ __launch_bounds__(256) void gemm_mfma(
        const float* __restrict__ X,
        const unsigned short* __restrict__ Whi,
        const unsigned short* __restrict__ Wlo, int matbase,
        const float* __restrict__ bl, const float* __restrict__ br,
        float* __restrict__ xl, float* __restrict__ xr, int nrows) {
    const float* bias = blockIdx.y ? br : bl;
    float*       Out  = blockIdx.y ? xr : xl;
    const unsigned short* hp = Whi + ((size_t)(matbase + blockIdx.y) * 16384);
    const unsigned short* lp = Wlo + ((size_t)(matbase + blockIdx.y) * 16384);

    int w   = threadIdx.x >> 6;
    int l   = threadIdx.x & 63;
    int m15 = l & 15, g = l >> 4;
    int rowbase = blockIdx.x * 64 + w * 16;

    f32x4 acc[8];
    #pragma unroll
    for (int nf = 0; nf < 8; ++nf) acc[nf] = (f32x4){0.f, 0.f, 0.f, 0.f};

    #pragma unroll
    for (int kb = 0; kb < 4; ++kb) {
        int arow = rowbase + m15;
        float4 x0 = make_float4(0.f, 0.f, 0.f, 0.f), x1 = x0;
        if (arow < nrows) {
            const float* xp = &X[(size_t)arow * 128 + kb * 32 + g * 8];
            x0 = *(const float4*)xp;
            x1 = *(const float4*)(xp + 4);
        }
        float xv[8] = {x0.x, x0.y, x0.z, x0.w, x1.x, x1.y, x1.z, x1.w};
        bf16x8 ahi, alo;
        #pragma unroll
        for (int j = 0; j < 8; ++j) {
            unsigned short h = f2bf_rne(xv[j]);
            ahi[j] = (short)h;
            alo[j] = (short)f2bf_rne(xv[j] - bf2f(h));
        }
        #pragma unroll
        for (int nf = 0; nf < 8; ++nf) {
            size_t off = (((size_t)kb * 8 + nf) * 64 + l) * 8;
            bf16x8 bhi = *(const bf16x8*)&hp[off];
            bf16x8 blo = *(const bf16x8*)&lp[off];
            acc[nf] = __builtin_amdgcn_mfma_f32_16x16x32_bf16(ahi, bhi, acc[nf], 0, 0, 0);
            acc[nf] = __builtin_amdgcn_mfma_f32_16x16x32_bf16(ahi, blo, acc[nf], 0, 0, 0);
            acc[nf] = __builtin_amdgcn_mfma_f32_16x16x32_bf16(alo, bhi, acc[nf], 0, 0, 0);
        }
    }

    // C/D layout: col = lane&15, row = (lane>>4)*4 + reg
    #pragma unroll
    for (int nf = 0; nf < 8; ++nf) {
        int col = nf * 16 + m15;
        float b = bias[col];
        #pragma unroll
        for (int r = 0; r < 4; ++r) {
            int row = rowbase + g * 4 + r;
            if (row < nrows)
                Out[(size_t)row * 128 + col] = acc[nf][r] + b;
        }
    }
}

// ---------------------------------------------------------------------------
// Fused GATv2 aggregation — round-5 proven structure (4 groups x 16 lanes,
// ONE edge per group per iteration) + no-max softmax (shift-invariant;
// validated round 7: identical absmax) + DPP row-sum reduce (no LDS pipe).
// Optional fused output projection (layer 3).
// ---------------------------------------------------------------------------
__device__ __forceinline__ float dsel(float4 a, float4 x, float4 tp, float4 tn) {
    float r, v;
    v = a.x + x.x; r  = v * (v > 0.f ? tp.x : tn.x);
    v = a.y + x.y; r += v * (v > 0.f ? tp.y : tn.y);
    v = a.z + x.z; r += v * (v > 0.f ? tp.z : tn.z);
    v = a.w + x.w; r += v * (v > 0.f ? tp.w : tn.w);
    return r;
}

__global__ __launch_bounds__(256) void gat_aggregate(
        const float* __restrict__ xl, const float* __restrict__ xr,
        const int* __restrict__ rowptr, const int* __restrict__ esrc,
        const float* __restrict__ att, const float* __restrict__ bias,
        float* __restrict__ hout, int n, int do_relu,
        const float* __restrict__ Wout, const float* __restrict__ bout,
        float* __restrict__ out4) {
    int node = (int)((blockIdx.x * blockDim.x + threadIdx.x) >> 6);
    int lane = threadIdx.x & 63;
    if (node >= n) return;
    int g  = lane >> 4;
    int gl = lane & 15;
    int c0 = gl * 4;

    const float* xrp = &xr[(size_t)node * 128];
    float4 xr0 = *(const float4*)&xrp[c0];
    float4 xr1 = *(const float4*)&xrp[64 + c0];
    float4 atp0 = *(const float4*)&att[c0];
    float4 atp1 = *(const float4*)&att[64 + c0];
    float4 atn0 = make_float4(NEG * atp0.x, NEG * atp0.y, NEG * atp0.z, NEG * atp0.w);
    float4 atn1 = make_float4(NEG * atp1.x, NEG * atp1.y, NEG * atp1.z, NEG * atp1.w);

    float s0 = 0.f, s1 = 0.f;
    float4 acc0 = make_float4(0.f, 0.f, 0.f, 0.f);
    float4 acc1 = make_float4(0.f, 0.f, 0.f, 0.f);

    int pbeg = rowptr[node], pend = rowptr[node + 1];
    for (int p = pbeg + g; p < pend; p += 4) {
        int s = esrc[p];
        const float* xlp = &xl[(size_t)s * 128];
        float4 a0 = *(const float4*)&xlp[c0];
        float4 a1 = *(const float4*)&xlp[64 + c0];

        float t0 = dsel(a0, xr0, atp0, atn0);
        float t1 = dsel(a1, xr1, atp1, atn1);
        t0 = rowsum16(t0);
        t1 = rowsum16(t1);

        float p0 = __expf(fminf(t0, 80.f));
        float p1 = __expf(fminf(t1, 80.f));
        s0 += p0;  s1 += p1;
        acc0.x += p0 * a0.x;  acc0.y += p0 * a0.y;
        acc0.z += p0 * a0.z;  acc0.w += p0 * a0.w;
        acc1.x += p1 * a1.x;  acc1.y += p1 * a1.y;
        acc1.z += p1 * a1.z;  acc1.w += p1 * a1.w;
    }

    // plain butterfly sum across the 4 groups (xor 16 then 32)
    #pragma unroll
    for (int off = 16; off <= 32; off <<= 1) {
        s0 += __shfl_xor(s0, off, 64);
        s1 += __shfl_xor(s1, off, 64);
        acc0.x += __shfl_xor(acc0.x, off, 64); acc0.y += __shfl_xor(acc0.y, off, 64);
        acc0.z += __shfl_xor(acc0.z, off, 64); acc0.w += __shfl_xor(acc0.w, off, 64);
        acc1.x += __shfl_xor(acc1.x, off, 64); acc1.y += __shfl_xor(acc1.y, off, 64);
        acc1.z += __shfl_xor(acc1.z, off, 64); acc1.w += __shfl_xor(acc1.w, off, 64);
    }

    float inv0 = 1.f / s0, inv1 = 1.f / s1;

    if (out4) {
        // fused output projection: all lanes hold the full merged state.
        float o0[4], o1[4];
        float a0v[4] = {acc0.x, acc0.y, acc0.z, acc0.w};
        float a1v[4] = {acc1.x, acc1.y, acc1.z, acc1.w};
        #pragma unroll
        for (int i = 0; i < 4; ++i) {
            o0[i] = a0v[i] * inv0 + bias[c0 + i];
            o1[i] = a1v[i] * inv1 + bias[64 + c0 + i];
            if (do_relu) { o0[i] = fmaxf(o0[i], 0.f); o1[i] = fmaxf(o1[i], 0.f); }
        }
        float p0 = 0.f, p1 = 0.f, p2 = 0.f, p3 = 0.f;
        #pragma unroll
        for (int i = 0; i < 4; ++i) {
            float4 w = *(const float4*)&Wout[(c0 + i) * 4];
            p0 += o0[i] * w.x; p1 += o0[i] * w.y; p2 += o0[i] * w.z; p3 += o0[i] * w.w;
        }
        #pragma unroll
        for (int i = 0; i < 4; ++i) {
            float4 w = *(const float4*)&Wout[(64 + c0 + i) * 4];
            p0 += o1[i] * w.x; p1 += o1[i] * w.y; p2 += o1[i] * w.z; p3 += o1[i] * w.w;
        }
        p0 = rowsum16(p0); p1 = rowsum16(p1);
        p2 = rowsum16(p2); p3 = rowsum16(p3);
        if (lane == 0) {
            float4 o = make_float4(p0 + bout[0], p1 + bout[1],
                                   p2 + bout[2], p3 + bout[3]);
            *(float4*)&out4[(size_t)node * 4] = o;
        }
        return;
    }

    if (g == 0) {
        float4 vb = *(const float4*)&bias[c0];
        float4 o = make_float4(acc0.x * inv0 + vb.x, acc0.y * inv0 + vb.y,
                               acc0.z * inv0 + vb.z, acc0.w * inv0 + vb.w);
        if (do_relu) {
            o.x = fmaxf(o.x, 0.f); o.y = fmaxf(o.y, 0.f);
            o.z = fmaxf(o.z, 0.f); o.w = fmaxf(o.w, 0.f);
        }
        *(float4*)&hout[(size_t)node * 128 + c0] = o;
    } else if (g == 1) {
        float4 vb = *(const float4*)&bias[64 + c0];
        float4 o = make_float4(acc1.x * inv1 + vb.x, acc1.y * inv1 + vb.y,
                               acc1.z * inv1 + vb.z, acc1.w * inv1 + vb.w);
        if (do_relu) {
            o.x = fmaxf(o.x, 0.f); o.y = fmaxf(o.y, 0.f);
            o.z = fmaxf(o.z, 0.f); o.w = fmaxf(o.w, 0.f);
        }
        *(float4*)&hout[(size_t)node * 128 + 64 + c0] = o;
    }
}

// ---------------------------------------------------------------------------
extern "C" void kernel_launch(void* const* d_in, const int* in_sizes, int n_in,
                              void* d_out, int out_size, void* d_ws,
                              size_t ws_size, hipStream_t stream) {
    // setup_inputs order:
    //  0:x 1:edge_index 2:W1l 3:b1l 4:W1r 5:b1r 6:att1 7:bias1
    //  8:W2l 9:b2l 10:W2r 11:b2r 12:att2 13:bias2
    // 14:W3l 15:b3l 16:W3r 17:b3r 18:att3 19:bias3 20:Wout 21:bout
    const float* x    = (const float*)d_in[0];
    const int*   ei   = (const int*)  d_in[1];
    const float* W1l  = (const float*)d_in[2];
    const float* b1l  = (const float*)d_in[3];
    const float* W1r  = (const float*)d_in[4];
    const float* b1r  = (const float*)d_in[5];
    const float* att1 = (const float*)d_in[6];
    const float* bias1= (const float*)d_in[7];
    const float* W2l  = (const float*)d_in[8];
    const float* b2l  = (const float*)d_in[9];
    const float* W2r  = (const float*)d_in[10];
    const float* b2r  = (const float*)d_in[11];
    const float* att2 = (const float*)d_in[12];
    const float* bias2= (const float*)d_in[13];
    const float* W3l  = (const float*)d_in[14];
    const float* b3l  = (const float*)d_in[15];
    const float* W3r  = (const float*)d_in[16];
    const float* b3r  = (const float*)d_in[17];
    const float* att3 = (const float*)d_in[18];
    const float* bias3= (const float*)d_in[19];
    const float* Wout = (const float*)d_in[20];
    const float* bout = (const float*)d_in[21];

    int N    = in_sizes[0] / DIN;
    int E    = in_sizes[1] / 2;
    int Etot = E + N;

    float* h      = (float*)d_ws;
    float* xl     = h  + (size_t)N * HC;
    float* xr     = xl + (size_t)N * HC;
    unsigned short* whi = (unsigned short*)(xr + (size_t)N * HC);
    unsigned short* wlo = whi + 6 * 16384;
    int*   esrc   = (int*)(wlo + 6 * 16384);
    int*   rowptr = esrc + Etot;
    int*   cursor = rowptr + (((N + 1) + 3) & ~3);   // keep cursor 16B-aligned
    int*   counts = cursor + N;

    hipMemsetAsync(counts, 0, (size_t)N * sizeof(int), stream);
    hist_kernel<<<(Etot + 255) / 256, 256, 0, stream>>>(ei, E, N, counts);
    scan_kernel<<<1, 1024, 0, stream>>>(counts, rowptr, cursor, N);
    scatter_kernel<<<(Etot + 255) / 256, 256, 0, stream>>>(ei, E, N, cursor, esrc);
    prep_w<<<dim3(8, 6), 256, 0, stream>>>(W1l, W1r, W2l, W2r, W3l, W3r, whi, wlo);

    dim3 gemm_grid((N + 63) / 64, 2);
    int  agg_grid = (N + 3) / 4;

    gemm_mfma<<<gemm_grid, 256, 0, stream>>>(x, whi, wlo, 0, b1l, b1r, xl, xr, N);
    gat_aggregate<<<agg_grid, 256, 0, stream>>>(xl, xr, rowptr, esrc, att1, bias1,
                                                h, N, 1, nullptr, nullptr, nullptr);
    gemm_mfma<<<gemm_grid, 256, 0, stream>>>(h, whi, wlo, 2, b2l, b2r, xl, xr, N);
    gat_aggregate<<<agg_grid, 256, 0, stream>>>(xl, xr, rowptr, esrc, att2, bias2,
                                                h, N, 1, nullptr, nullptr, nullptr);
    gemm_mfma<<<gemm_grid, 256, 0, stream>>>(h, whi, wlo, 4, b3l, b3r, xl, xr, N);
    // layer 3: fused relu + output projection, h never materialized
    gat_aggregate<<<agg_grid, 256, 0, stream>>>(xl, xr, rowptr, esrc, att3, bias3,
                                                nullptr, N, 1, Wout, bout,
                                                (float*)d_out);
}

// Round 9
// 400.546 us; speedup vs baseline: 1.1349x; 1.0467x over previous
//
#include <hip/hip_runtime.h>
#include <math.h>

#define DIN  128
#define HC   128
#define NEG  0.2f

typedef __attribute__((ext_vector_type(8))) short bf16x8;
typedef __attribute__((ext_vector_type(4))) float f32x4;

__device__ __forceinline__ unsigned short f2bf_rne(float x) {
    unsigned u = __float_as_uint(x);
    unsigned r = u + 0x7FFFu + ((u >> 16) & 1u);
    return (unsigned short)(r >> 16);
}
__device__ __forceinline__ float bf2f(unsigned short h) {
    return __uint_as_float(((unsigned)h) << 16);
}

// 16-lane (DPP-row) butterfly sum: xor1, xor2, xor7, xor15 — pure VALU.
template <int CTRL>
__device__ __forceinline__ float dpp_xadd(float x) {
    int r = __builtin_amdgcn_update_dpp(0, __float_as_int(x), CTRL, 0xF, 0xF, true);
    return x + __int_as_float(r);
}
__device__ __forceinline__ float rowsum16(float x) {
    x = dpp_xadd<0xB1>(x);   // lane ^ 1
    x = dpp_xadd<0x4E>(x);   // lane ^ 2
    x = dpp_xadd<0x141>(x);  // lane ^ 7
    x = dpp_xadd<0x140>(x);  // lane ^ 15
    return x;
}

// ---------------------------------------------------------------------------
// CSR build
// ---------------------------------------------------------------------------
__global__ void hist_kernel(const int* __restrict__ ei, int E, int N,
                            int* __restrict__ counts) {
    int i = blockIdx.x * blockDim.x + threadIdx.x;
    int Etot = E + N;
    if (i >= Etot) return;
    int dst = (i < E) ? ei[E + i] : (i - E);
    if (dst < 0 || dst >= N) return;
    atomicAdd(&counts[dst], 1);
}

__global__ void scan_kernel(const int* __restrict__ counts,
                            int* __restrict__ rowptr,
                            int* __restrict__ cursor, int n) {
    __shared__ int wsum[16];
    int tid  = threadIdx.x;          // 1024 threads
    int lane = tid & 63, wid = tid >> 6;
    int running = 0;
    for (int base = 0; base < n; base += 4096) {
        int i = base + tid * 4;
        int4 v = make_int4(0, 0, 0, 0);
        if (i < n) v = *(const int4*)&counts[i];   // n % 4 == 0
        int ssum = v.x + v.y + v.z + v.w;
        int x = ssum;
        #pragma unroll
        for (int off = 1; off < 64; off <<= 1) {
            int y = __shfl_up(x, off, 64);
            if (lane >= off) x += y;
        }
        if (lane == 63) wsum[wid] = x;
        __syncthreads();
        if (tid < 16) {
            int w = wsum[tid];
            #pragma unroll
            for (int off = 1; off < 16; off <<= 1) {
                int y = __shfl_up(w, off, 64);
                if (tid >= off) w += y;
            }
            wsum[tid] = w;
        }
        __syncthreads();
        int excl = running + (wid ? wsum[wid - 1] : 0) + (x - ssum);
        if (i < n) {
            int4 r;
            r.x = excl;
            r.y = r.x + v.x;
            r.z = r.y + v.y;
            r.w = r.z + v.z;
            *(int4*)&rowptr[i] = r;
            *(int4*)&cursor[i] = r;
        }
        running += wsum[15];
        __syncthreads();
    }
    if (tid == 0) rowptr[n] = running;
}

__global__ void scatter_kernel(const int* __restrict__ ei, int E, int N,
                               int* __restrict__ cursor,
                               int* __restrict__ esrc) {
    int i = blockIdx.x * blockDim.x + threadIdx.x;
    int Etot = E + N;
    if (i >= Etot) return;
    int src = (i < E) ? ei[i]     : (i - E);
    int dst = (i < E) ? ei[E + i] : (i - E);
    if (dst < 0 || dst >= N || src < 0 || src >= N) return;
    int pos = atomicAdd(&cursor[dst], 1);
    esrc[pos] = src;
}

// ---------------------------------------------------------------------------
// W prep: split each 128x128 W into bf16 hi/lo, packed in MFMA B-fragment
// order: slot (kb,nf,lane,j) = W[kb*32 + (lane>>4)*8 + j][nf*16 + (lane&15)].
// ---------------------------------------------------------------------------
__global__ __launch_bounds__(256) void prep_w(
        const float* __restrict__ W1l, const float* __restrict__ W1r,
        const float* __restrict__ W2l, const float* __restrict__ W2r,
        const float* __restrict__ W3l, const float* __restrict__ W3r,
        unsigned short* __restrict__ hi, unsigned short* __restrict__ lo) {
    int m = blockIdx.y;
    const float* W = (m == 0) ? W1l : (m == 1) ? W1r : (m == 2) ? W2l
                   : (m == 3) ? W2r : (m == 4) ? W3l : W3r;
    int t = blockIdx.x * 256 + threadIdx.x;    // 0..2047 (grid.x = 8)
    int kb = t >> 9, nf = (t >> 6) & 7, l = t & 63;
    int col = nf * 16 + (l & 15);
    int k0  = kb * 32 + (l >> 4) * 8;
    size_t ob = ((size_t)m * 2048 + t) * 8;
    #pragma unroll
    for (int j = 0; j < 8; ++j) {
        float v = W[(size_t)(k0 + j) * 128 + col];
        unsigned short h = f2bf_rne(v);
        hi[ob + j] = h;
        lo[ob + j] = f2bf_rne(v - bf2f(h));
    }
}

// ---------------------------------------------------------------------------
// Dual MFMA GEMM (split-bf16, 3 terms): xl = X@Wl + bl AND xr = X@Wr + br in
// one pass — X read once, A fragments converted once, shared by 6 MFMAs.
// Explicit dual pointer streams (no runtime-selected W pointer: the round-3
// single-stream variant made the unroller spill to 256 VGPR).
// Block = 4 waves; wave w computes rows [bx*64 + w*16, +16) x all 128 cols.
// ---------------------------------------------------------------------------
__global__ __launch_bounds__(256) void gemm_mfma_dual(
        const float* __restrict__ X,
        const unsigned short* __restrict__ Whi,
        const unsigned short* __restrict__ Wlo, int matbase,
        const float* __restrict__ bl, const float* __restrict__ br,
        float* __restrict__ xl, float* __restrict__ xr, int nrows) {
    const unsigned short* hpl = Whi + ((size_t)(matbase + 0) * 16384);
    const unsigned short* lpl = Wlo + ((size_t)(matbase + 0) * 16384);
    const unsigned short* hpr = Whi + ((size_t)(matbase + 1) * 16384);
    const unsigned short* lpr = Wlo + ((size_t)(matbase + 1) * 16384);

    int w   = threadIdx.x >> 6;
    int l   = threadIdx.x & 63;
    int m15 = l & 15, g = l >> 4;
    int rowbase = blockIdx.x * 64 + w * 16;

    f32x4 accl[8], accr[8];
    #pragma unroll
    for (int nf = 0; nf < 8; ++nf) {
        accl[nf] = (f32x4){0.f, 0.f, 0.f, 0.f};
        accr[nf] = (f32x4){0.f, 0.f, 0.f, 0.f};
    }

    #pragma unroll
    for (int kb = 0; kb < 4; ++kb) {
        int arow = rowbase + m15;
        float4 x0 = make_float4(0.f, 0.f, 0.f, 0.f), x1 = x0;
        if (arow < nrows) {
            const float* xp = &X[(size_t)arow * 128 + kb * 32 + g * 8];
            x0 = *(const float4*)xp;
            x1 = *(const float4*)(xp + 4);
        }
        float xv[8] = {x0.x, x0.y, x0.z, x0.w, x1.x, x1.y, x1.z, x1.w};
        bf16x8 ahi, alo;
        #pragma unroll
        for (int j = 0; j < 8; ++j) {
            unsigned short h = f2bf_rne(xv[j]);
            ahi[j] = (short)h;
            alo[j] = (short)f2bf_rne(xv[j] - bf2f(h));
        }
        #pragma unroll
        for (int nf = 0; nf < 8; ++nf) {
            size_t off = (((size_t)kb * 8 + nf) * 64 + l) * 8;
            bf16x8 bhl = *(const bf16x8*)&hpl[off];
            bf16x8 bll = *(const bf16x8*)&lpl[off];
            bf16x8 bhr = *(const bf16x8*)&hpr[off];
            bf16x8 blr = *(const bf16x8*)&lpr[off];
            accl[nf] = __builtin_amdgcn_mfma_f32_16x16x32_bf16(ahi, bhl, accl[nf], 0, 0, 0);
            accl[nf] = __builtin_amdgcn_mfma_f32_16x16x32_bf16(ahi, bll, accl[nf], 0, 0, 0);
            accl[nf] = __builtin_amdgcn_mfma_f32_16x16x32_bf16(alo, bhl, accl[nf], 0, 0, 0);
            accr[nf] = __builtin_amdgcn_mfma_f32_16x16x32_bf16(ahi, bhr, accr[nf], 0, 0, 0);
            accr[nf] = __builtin_amdgcn_mfma_f32_16x16x32_bf16(ahi, blr, accr[nf], 0, 0, 0);
            accr[nf] = __builtin_amdgcn_mfma_f32_16x16x32_bf16(alo, bhr, accr[nf], 0, 0, 0);
        }
    }

    // C/D layout: col = lane&15, row = (lane>>4)*4 + reg
    #pragma unroll
    for (int nf = 0; nf < 8; ++nf) {
        int col = nf * 16 + m15;
        float vbl = bl[col];
        float vbr = br[col];
        #pragma unroll
        for (int r = 0; r < 4; ++r) {
            int row = rowbase + g * 4 + r;
            if (row < nrows) {
                xl[(size_t)row * 128 + col] = accl[nf][r] + vbl;
                xr[(size_t)row * 128 + col] = accr[nf][r] + vbr;
            }
        }
    }
}

// ---------------------------------------------------------------------------
// Fused GATv2 aggregation — 4 groups x 16 lanes, no-max softmax, DPP rowsum,
// ROTATED SOFTWARE PREFETCH: edge p+4's xl row is loaded before edge p is
// consumed, so each group keeps 2 gathers in flight (commutative no-max
// accumulation => no serial-update penalty). Optional fused out projection.
// ---------------------------------------------------------------------------
__device__ __forceinline__ float dsel(float4 a, float4 x, float4 tp, float4 tn) {
    float r, v;
    v = a.x + x.x; r  = v * (v > 0.f ? tp.x : tn.x);
    v = a.y + x.y; r += v * (v > 0.f ? tp.y : tn.y);
    v = a.z + x.z; r += v * (v > 0.f ? tp.z : tn.z);
    v = a.w + x.w; r += v * (v > 0.f ? tp.w : tn.w);
    return r;
}

__global__ __launch_bounds__(256) void gat_aggregate(
        const float* __restrict__ xl, const float* __restrict__ xr,
        const int* __restrict__ rowptr, const int* __restrict__ esrc,
        const float* __restrict__ att, const float* __restrict__ bias,
        float* __restrict__ hout, int n, int do_relu,
        const float* __restrict__ Wout, const float* __restrict__ bout,
        float* __restrict__ out4) {
    int node = (int)((blockIdx.x * blockDim.x + threadIdx.x) >> 6);
    int lane = threadIdx.x & 63;
    if (node >= n) return;
    int g  = lane >> 4;
    int gl = lane & 15;
    int c0 = gl * 4;

    const float* xrp = &xr[(size_t)node * 128];
    float4 xr0 = *(const float4*)&xrp[c0];
    float4 xr1 = *(const float4*)&xrp[64 + c0];
    float4 atp0 = *(const float4*)&att[c0];
    float4 atp1 = *(const float4*)&att[64 + c0];
    float4 atn0 = make_float4(NEG * atp0.x, NEG * atp0.y, NEG * atp0.z, NEG * atp0.w);
    float4 atn1 = make_float4(NEG * atp1.x, NEG * atp1.y, NEG * atp1.z, NEG * atp1.w);

    float s0 = 0.f, s1 = 0.f;
    float4 acc0 = make_float4(0.f, 0.f, 0.f, 0.f);
    float4 acc1 = make_float4(0.f, 0.f, 0.f, 0.f);

    int pbeg = rowptr[node], pend = rowptr[node + 1];
    int p = pbeg + g;
    bool valid = p < pend;
    float4 a0c = make_float4(0.f, 0.f, 0.f, 0.f), a1c = a0c;
    if (valid) {
        const float* xp = &xl[(size_t)esrc[p] * 128];
        a0c = *(const float4*)&xp[c0];
        a1c = *(const float4*)&xp[64 + c0];
    }
    while (valid) {
        int  pn = p + 4;
        bool vn = pn < pend;                 // uniform within 16-lane group
        float4 a0n = make_float4(0.f, 0.f, 0.f, 0.f), a1n = a0n;
        if (vn) {                            // issue next gather BEFORE compute
            const float* xp = &xl[(size_t)esrc[pn] * 128];
            a0n = *(const float4*)&xp[c0];
            a1n = *(const float4*)&xp[64 + c0];
        }

        float t0 = rowsum16(dsel(a0c, xr0, atp0, atn0));
        float t1 = rowsum16(dsel(a1c, xr1, atp1, atn1));
        float p0 = __expf(fminf(t0, 80.f));
        float p1 = __expf(fminf(t1, 80.f));
        s0 += p0;  s1 += p1;
        acc0.x += p0 * a0c.x;  acc0.y += p0 * a0c.y;
        acc0.z += p0 * a0c.z;  acc0.w += p0 * a0c.w;
        acc1.x += p1 * a1c.x;  acc1.y += p1 * a1c.y;
        acc1.z += p1 * a1c.z;  acc1.w += p1 * a1c.w;

        a0c = a0n; a1c = a1n; p = pn; valid = vn;
    }

    // butterfly sum across the 4 groups (xor 16 then 32)
    #pragma unroll
    for (int off = 16; off <= 32; off <<= 1) {
        s0 += __shfl_xor(s0, off, 64);
        s1 += __shfl_xor(s1, off, 64);
        acc0.x += __shfl_xor(acc0.x, off, 64); acc0.y += __shfl_xor(acc0.y, off, 64);
        acc0.z += __shfl_xor(acc0.z, off, 64); acc0.w += __shfl_xor(acc0.w, off, 64);
        acc1.x += __shfl_xor(acc1.x, off, 64); acc1.y += __shfl_xor(acc1.y, off, 64);
        acc1.z += __shfl_xor(acc1.z, off, 64); acc1.w += __shfl_xor(acc1.w, off, 64);
    }

    float inv0 = 1.f / s0, inv1 = 1.f / s1;

    if (out4) {
        float o0[4], o1[4];
        float a0v[4] = {acc0.x, acc0.y, acc0.z, acc0.w};
        float a1v[4] = {acc1.x, acc1.y, acc1.z, acc1.w};
        #pragma unroll
        for (int i = 0; i < 4; ++i) {
            o0[i] = a0v[i] * inv0 + bias[c0 + i];
            o1[i] = a1v[i] * inv1 + bias[64 + c0 + i];
            if (do_relu) { o0[i] = fmaxf(o0[i], 0.f); o1[i] = fmaxf(o1[i], 0.f); }
        }
        float p0 = 0.f, p1 = 0.f, p2 = 0.f, p3 = 0.f;
        #pragma unroll
        for (int i = 0; i < 4; ++i) {
            float4 w = *(const float4*)&Wout[(c0 + i) * 4];
            p0 += o0[i] * w.x; p1 += o0[i] * w.y; p2 += o0[i] * w.z; p3 += o0[i] * w.w;
        }
        #pragma unroll
        for (int i = 0; i < 4; ++i) {
            float4 w = *(const float4*)&Wout[(64 + c0 + i) * 4];
            p0 += o1[i] * w.x; p1 += o1[i] * w.y; p2 += o1[i] * w.z; p3 += o1[i] * w.w;
        }
        p0 = rowsum16(p0); p1 = rowsum16(p1);
        p2 = rowsum16(p2); p3 = rowsum16(p3);
        if (lane == 0) {
            float4 o = make_float4(p0 + bout[0], p1 + bout[1],
                                   p2 + bout[2], p3 + bout[3]);
            *(float4*)&out4[(size_t)node * 4] = o;
        }
        return;
    }

    if (g == 0) {
        float4 vb = *(const float4*)&bias[c0];
        float4 o = make_float4(acc0.x * inv0 + vb.x, acc0.y * inv0 + vb.y,
                               acc0.z * inv0 + vb.z, acc0.w * inv0 + vb.w);
        if (do_relu) {
            o.x = fmaxf(o.x, 0.f); o.y = fmaxf(o.y, 0.f);
            o.z = fmaxf(o.z, 0.f); o.w = fmaxf(o.w, 0.f);
        }
        *(float4*)&hout[(size_t)node * 128 + c0] = o;
    } else if (g == 1) {
        float4 vb = *(const float4*)&bias[64 + c0];
        float4 o = make_float4(acc1.x * inv1 + vb.x, acc1.y * inv1 + vb.y,
                               acc1.z * inv1 + vb.z, acc1.w * inv1 + vb.w);
        if (do_relu) {
            o.x = fmaxf(o.x, 0.f); o.y = fmaxf(o.y, 0.f);
            o.z = fmaxf(o.z, 0.f); o.w = fmaxf(o.w, 0.f);
        }
        *(float4*)&hout[(size_t)node * 128 + 64 + c0] = o;
    }
}

// ---------------------------------------------------------------------------
extern "C" void kernel_launch(void* const* d_in, const int* in_sizes, int n_in,
                              void* d_out, int out_size, void* d_ws,
                              size_t ws_size, hipStream_t stream) {
    // setup_inputs order:
    //  0:x 1:edge_index 2:W1l 3:b1l 4:W1r 5:b1r 6:att1 7:bias1
    //  8:W2l 9:b2l 10:W2r 11:b2r 12:att2 13:bias2
    // 14:W3l 15:b3l 16:W3r 17:b3r 18:att3 19:bias3 20:Wout 21:bout
    const float* x    = (const float*)d_in[0];
    const int*   ei   = (const int*)  d_in[1];
    const float* W1l  = (const float*)d_in[2];
    const float* b1l  = (const float*)d_in[3];
    const float* W1r  = (const float*)d_in[4];
    const float* b1r  = (const float*)d_in[5];
    const float* att1 = (const float*)d_in[6];
    const float* bias1= (const float*)d_in[7];
    const float* W2l  = (const float*)d_in[8];
    const float* b2l  = (const float*)d_in[9];
    const float* W2r  = (const float*)d_in[10];
    const float* b2r  = (const float*)d_in[11];
    const float* att2 = (const float*)d_in[12];
    const float* bias2= (const float*)d_in[13];
    const float* W3l  = (const float*)d_in[14];
    const float* b3l  = (const float*)d_in[15];
    const float* W3r  = (const float*)d_in[16];
    const float* b3r  = (const float*)d_in[17];
    const float* att3 = (const float*)d_in[18];
    const float* bias3= (const float*)d_in[19];
    const float* Wout = (const float*)d_in[20];
    const float* bout = (const float*)d_in[21];

    int N    = in_sizes[0] / DIN;
    int E    = in_sizes[1] / 2;
    int Etot = E + N;

    float* h      = (float*)d_ws;
    float* xl     = h  + (size_t)N * HC;
    float* xr     = xl + (size_t)N * HC;
    unsigned short* whi = (unsigned short*)(xr + (size_t)N * HC);
    unsigned short* wlo = whi + 6 * 16384;
    int*   esrc   = (int*)(wlo + 6 * 16384);
    int*   rowptr = esrc + Etot;
    int*   cursor = rowptr + (((N + 1) + 3) & ~3);   // keep cursor 16B-aligned
    int*   counts = cursor + N;

    hipMemsetAsync(counts, 0, (size_t)N * sizeof(int), stream);
    hist_kernel<<<(Etot + 255) / 256, 256, 0, stream>>>(ei, E, N, counts);
    scan_kernel<<<1, 1024, 0, stream>>>(counts, rowptr, cursor, N);
    scatter_kernel<<<(Etot + 255) / 256, 256, 0, stream>>>(ei, E, N, cursor, esrc);
    prep_w<<<dim3(8, 6), 256, 0, stream>>>(W1l, W1r, W2l, W2r, W3l, W3r, whi, wlo);

    int gemm_grid = (N + 63) / 64;
    int agg_grid  = (N + 3) / 4;

    gemm_mfma_dual<<<gemm_grid, 256, 0, stream>>>(x, whi, wlo, 0, b1l, b1r, xl, xr, N);
    gat_aggregate<<<agg_grid, 256, 0, stream>>>(xl, xr, rowptr, esrc, att1, bias1,
                                                h, N, 1, nullptr, nullptr, nullptr);
    gemm_mfma_dual<<<gemm_grid, 256, 0, stream>>>(h, whi, wlo, 2, b2l, b2r, xl, xr, N);
    gat_aggregate<<<agg_grid, 256, 0, stream>>>(xl, xr, rowptr, esrc, att2, bias2,
                                                h, N, 1, nullptr, nullptr, nullptr);
    gemm_mfma_dual<<<gemm_grid, 256, 0, stream>>>(h, whi, wlo, 4, b3l, b3r, xl, xr, N);
    // layer 3: fused relu + output projection, h never materialized
    gat_aggregate<<<agg_grid, 256, 0, stream>>>(xl, xr, rowptr, esrc, att3, bias3,
                                                nullptr, N, 1, Wout, bout,
                                                (float*)d_out);
}

// Round 10
// 356.357 us; speedup vs baseline: 1.2757x; 1.1240x over previous
//
#include <hip/hip_runtime.h>
#include <math.h>

#define DIN  128
#define HC   128
#define NEG  0.2f

typedef __attribute__((ext_vector_type(8))) short bf16x8;
typedef __attribute__((ext_vector_type(4))) float f32x4;
typedef __attribute__((ext_vector_type(4))) _Float16 half4;

__device__ __forceinline__ unsigned short f2bf_rne(float x) {
    unsigned u = __float_as_uint(x);
    unsigned r = u + 0x7FFFu + ((u >> 16) & 1u);
    return (unsigned short)(r >> 16);
}
__device__ __forceinline__ float bf2f(unsigned short h) {
    return __uint_as_float(((unsigned)h) << 16);
}

// 16-lane (DPP-row) butterfly sum: xor1, xor2, xor7, xor15 — pure VALU.
template <int CTRL>
__device__ __forceinline__ float dpp_xadd(float x) {
    int r = __builtin_amdgcn_update_dpp(0, __float_as_int(x), CTRL, 0xF, 0xF, true);
    return x + __int_as_float(r);
}
__device__ __forceinline__ float rowsum16(float x) {
    x = dpp_xadd<0xB1>(x);   // lane ^ 1
    x = dpp_xadd<0x4E>(x);   // lane ^ 2
    x = dpp_xadd<0x141>(x);  // lane ^ 7
    x = dpp_xadd<0x140>(x);  // lane ^ 15
    return x;
}

// ---------------------------------------------------------------------------
// CSR build
// ---------------------------------------------------------------------------
__global__ void hist_kernel(const int* __restrict__ ei, int E, int N,
                            int* __restrict__ counts) {
    int i = blockIdx.x * blockDim.x + threadIdx.x;
    int Etot = E + N;
    if (i >= Etot) return;
    int dst = (i < E) ? ei[E + i] : (i - E);
    if (dst < 0 || dst >= N) return;
    atomicAdd(&counts[dst], 1);
}

__global__ void scan_kernel(const int* __restrict__ counts,
                            int* __restrict__ rowptr,
                            int* __restrict__ cursor, int n) {
    __shared__ int wsum[16];
    int tid  = threadIdx.x;          // 1024 threads
    int lane = tid & 63, wid = tid >> 6;
    int running = 0;
    for (int base = 0; base < n; base += 4096) {
        int i = base + tid * 4;
        int4 v = make_int4(0, 0, 0, 0);
        if (i < n) v = *(const int4*)&counts[i];   // n % 4 == 0
        int ssum = v.x + v.y + v.z + v.w;
        int x = ssum;
        #pragma unroll
        for (int off = 1; off < 64; off <<= 1) {
            int y = __shfl_up(x, off, 64);
            if (lane >= off) x += y;
        }
        if (lane == 63) wsum[wid] = x;
        __syncthreads();
        if (tid < 16) {
            int w = wsum[tid];
            #pragma unroll
            for (int off = 1; off < 16; off <<= 1) {
                int y = __shfl_up(w, off, 64);
                if (tid >= off) w += y;
            }
            wsum[tid] = w;
        }
        __syncthreads();
        int excl = running + (wid ? wsum[wid - 1] : 0) + (x - ssum);
        if (i < n) {
            int4 r;
            r.x = excl;
            r.y = r.x + v.x;
            r.z = r.y + v.y;
            r.w = r.z + v.z;
            *(int4*)&rowptr[i] = r;
            *(int4*)&cursor[i] = r;
        }
        running += wsum[15];
        __syncthreads();
    }
    if (tid == 0) rowptr[n] = running;
}

__global__ void scatter_kernel(const int* __restrict__ ei, int E, int N,
                               int* __restrict__ cursor,
                               int* __restrict__ esrc) {
    int i = blockIdx.x * blockDim.x + threadIdx.x;
    int Etot = E + N;
    if (i >= Etot) return;
    int src = (i < E) ? ei[i]     : (i - E);
    int dst = (i < E) ? ei[E + i] : (i - E);
    if (dst < 0 || dst >= N || src < 0 || src >= N) return;
    int pos = atomicAdd(&cursor[dst], 1);
    esrc[pos] = src;
}

// ---------------------------------------------------------------------------
// W prep: split each 128x128 W into bf16 hi/lo, packed in MFMA B-fragment
// order: slot (kb,nf,lane,j) = W[kb*32 + (lane>>4)*8 + j][nf*16 + (lane&15)].
// ---------------------------------------------------------------------------
__global__ __launch_bounds__(256) void prep_w(
        const float* __restrict__ W1l, const float* __restrict__ W1r,
        const float* __restrict__ W2l, const float* __restrict__ W2r,
        const float* __restrict__ W3l, const float* __restrict__ W3r,
        unsigned short* __restrict__ hi, unsigned short* __restrict__ lo) {
    int m = blockIdx.y;
    const float* W = (m == 0) ? W1l : (m == 1) ? W1r : (m == 2) ? W2l
                   : (m == 3) ? W2r : (m == 4) ? W3l : W3r;
    int t = blockIdx.x * 256 + threadIdx.x;    // 0..2047 (grid.x = 8)
    int kb = t >> 9, nf = (t >> 6) & 7, l = t & 63;
    int col = nf * 16 + (l & 15);
    int k0  = kb * 32 + (l >> 4) * 8;
    size_t ob = ((size_t)m * 2048 + t) * 8;
    #pragma unroll
    for (int j = 0; j < 8; ++j) {
        float v = W[(size_t)(k0 + j) * 128 + col];
        unsigned short h = f2bf_rne(v);
        hi[ob + j] = h;
        lo[ob + j] = f2bf_rne(v - bf2f(h));
    }
}

// ---------------------------------------------------------------------------
// Dual MFMA GEMM (split-bf16, 3 terms): xl = X@Wl + bl (stored FP16, it is
// the gathered array — halves compulsory per-XCD L2-fill traffic) and
// xr = X@Wr + br (FP32, streamed once). X read once, A fragments shared.
// ---------------------------------------------------------------------------
__global__ __launch_bounds__(256) void gemm_mfma_dual(
        const float* __restrict__ X,
        const unsigned short* __restrict__ Whi,
        const unsigned short* __restrict__ Wlo, int matbase,
        const float* __restrict__ bl, const float* __restrict__ br,
        _Float16* __restrict__ xlh, float* __restrict__ xr, int nrows) {
    const unsigned short* hpl = Whi + ((size_t)(matbase + 0) * 16384);
    const unsigned short* lpl = Wlo + ((size_t)(matbase + 0) * 16384);
    const unsigned short* hpr = Whi + ((size_t)(matbase + 1) * 16384);
    const unsigned short* lpr = Wlo + ((size_t)(matbase + 1) * 16384);

    int w   = threadIdx.x >> 6;
    int l   = threadIdx.x & 63;
    int m15 = l & 15, g = l >> 4;
    int rowbase = blockIdx.x * 64 + w * 16;

    f32x4 accl[8], accr[8];
    #pragma unroll
    for (int nf = 0; nf < 8; ++nf) {
        accl[nf] = (f32x4){0.f, 0.f, 0.f, 0.f};
        accr[nf] = (f32x4){0.f, 0.f, 0.f, 0.f};
    }

    #pragma unroll
    for (int kb = 0; kb < 4; ++kb) {
        int arow = rowbase + m15;
        float4 x0 = make_float4(0.f, 0.f, 0.f, 0.f), x1 = x0;
        if (arow < nrows) {
            const float* xp = &X[(size_t)arow * 128 + kb * 32 + g * 8];
            x0 = *(const float4*)xp;
            x1 = *(const float4*)(xp + 4);
        }
        float xv[8] = {x0.x, x0.y, x0.z, x0.w, x1.x, x1.y, x1.z, x1.w};
        bf16x8 ahi, alo;
        #pragma unroll
        for (int j = 0; j < 8; ++j) {
            unsigned short h = f2bf_rne(xv[j]);
            ahi[j] = (short)h;
            alo[j] = (short)f2bf_rne(xv[j] - bf2f(h));
        }
        #pragma unroll
        for (int nf = 0; nf < 8; ++nf) {
            size_t off = (((size_t)kb * 8 + nf) * 64 + l) * 8;
            bf16x8 bhl = *(const bf16x8*)&hpl[off];
            bf16x8 bll = *(const bf16x8*)&lpl[off];
            bf16x8 bhr = *(const bf16x8*)&hpr[off];
            bf16x8 blr = *(const bf16x8*)&lpr[off];
            accl[nf] = __builtin_amdgcn_mfma_f32_16x16x32_bf16(ahi, bhl, accl[nf], 0, 0, 0);
            accl[nf] = __builtin_amdgcn_mfma_f32_16x16x32_bf16(ahi, bll, accl[nf], 0, 0, 0);
            accl[nf] = __builtin_amdgcn_mfma_f32_16x16x32_bf16(alo, bhl, accl[nf], 0, 0, 0);
            accr[nf] = __builtin_amdgcn_mfma_f32_16x16x32_bf16(ahi, bhr, accr[nf], 0, 0, 0);
            accr[nf] = __builtin_amdgcn_mfma_f32_16x16x32_bf16(ahi, blr, accr[nf], 0, 0, 0);
            accr[nf] = __builtin_amdgcn_mfma_f32_16x16x32_bf16(alo, bhr, accr[nf], 0, 0, 0);
        }
    }

    // C/D layout: col = lane&15, row = (lane>>4)*4 + reg
    #pragma unroll
    for (int nf = 0; nf < 8; ++nf) {
        int col = nf * 16 + m15;
        float vbl = bl[col];
        float vbr = br[col];
        #pragma unroll
        for (int r = 0; r < 4; ++r) {
            int row = rowbase + g * 4 + r;
            if (row < nrows) {
                xlh[(size_t)row * 128 + col] = (_Float16)(accl[nf][r] + vbl);
                xr[(size_t)row * 128 + col]  = accr[nf][r] + vbr;
            }
        }
    }
}

// ---------------------------------------------------------------------------
// Fused GATv2 aggregation — 4 groups x 16 lanes, no-max softmax, DPP rowsum,
// rotated prefetch. xl gathered as FP16 (8B/lane), converted in-register.
// Optional fused output projection (layer 3).
// ---------------------------------------------------------------------------
__device__ __forceinline__ float dsel(float4 a, float4 x, float4 tp, float4 tn) {
    float r, v;
    v = a.x + x.x; r  = v * (v > 0.f ? tp.x : tn.x);
    v = a.y + x.y; r += v * (v > 0.f ? tp.y : tn.y);
    v = a.z + x.z; r += v * (v > 0.f ? tp.z : tn.z);
    v = a.w + x.w; r += v * (v > 0.f ? tp.w : tn.w);
    return r;
}
__device__ __forceinline__ float4 h2f4(half4 h) {
    return make_float4((float)h.x, (float)h.y, (float)h.z, (float)h.w);
}

__global__ __launch_bounds__(256) void gat_aggregate(
        const _Float16* __restrict__ xlh, const float* __restrict__ xr,
        const int* __restrict__ rowptr, const int* __restrict__ esrc,
        const float* __restrict__ att, const float* __restrict__ bias,
        float* __restrict__ hout, int n, int do_relu,
        const float* __restrict__ Wout, const float* __restrict__ bout,
        float* __restrict__ out4) {
    int node = (int)((blockIdx.x * blockDim.x + threadIdx.x) >> 6);
    int lane = threadIdx.x & 63;
    if (node >= n) return;
    int g  = lane >> 4;
    int gl = lane & 15;
    int c0 = gl * 4;

    const float* xrp = &xr[(size_t)node * 128];
    float4 xr0 = *(const float4*)&xrp[c0];
    float4 xr1 = *(const float4*)&xrp[64 + c0];
    float4 atp0 = *(const float4*)&att[c0];
    float4 atp1 = *(const float4*)&att[64 + c0];
    float4 atn0 = make_float4(NEG * atp0.x, NEG * atp0.y, NEG * atp0.z, NEG * atp0.w);
    float4 atn1 = make_float4(NEG * atp1.x, NEG * atp1.y, NEG * atp1.z, NEG * atp1.w);

    float s0 = 0.f, s1 = 0.f;
    float4 acc0 = make_float4(0.f, 0.f, 0.f, 0.f);
    float4 acc1 = make_float4(0.f, 0.f, 0.f, 0.f);

    int pbeg = rowptr[node], pend = rowptr[node + 1];
    int p = pbeg + g;
    bool valid = p < pend;
    half4 h0c = (half4)(_Float16)0.f, h1c = (half4)(_Float16)0.f;
    if (valid) {
        const _Float16* xp = &xlh[(size_t)esrc[p] * 128];
        h0c = *(const half4*)&xp[c0];
        h1c = *(const half4*)&xp[64 + c0];
    }
    while (valid) {
        int  pn = p + 4;
        bool vn = pn < pend;                 // uniform within 16-lane group
        half4 h0n = (half4)(_Float16)0.f, h1n = (half4)(_Float16)0.f;
        if (vn) {                            // issue next gather BEFORE compute
            const _Float16* xp = &xlh[(size_t)esrc[pn] * 128];
            h0n = *(const half4*)&xp[c0];
            h1n = *(const half4*)&xp[64 + c0];
        }

        float4 a0 = h2f4(h0c), a1 = h2f4(h1c);
        float t0 = rowsum16(dsel(a0, xr0, atp0, atn0));
        float t1 = rowsum16(dsel(a1, xr1, atp1, atn1));
        float p0 = __expf(fminf(t0, 80.f));
        float p1 = __expf(fminf(t1, 80.f));
        s0 += p0;  s1 += p1;
        acc0.x += p0 * a0.x;  acc0.y += p0 * a0.y;
        acc0.z += p0 * a0.z;  acc0.w += p0 * a0.w;
        acc1.x += p1 * a1.x;  acc1.y += p1 * a1.y;
        acc1.z += p1 * a1.z;  acc1.w += p1 * a1.w;

        h0c = h0n; h1c = h1n; p = pn; valid = vn;
    }

    // butterfly sum across the 4 groups (xor 16 then 32)
    #pragma unroll
    for (int off = 16; off <= 32; off <<= 1) {
        s0 += __shfl_xor(s0, off, 64);
        s1 += __shfl_xor(s1, off, 64);
        acc0.x += __shfl_xor(acc0.x, off, 64); acc0.y += __shfl_xor(acc0.y, off, 64);
        acc0.z += __shfl_xor(acc0.z, off, 64); acc0.w += __shfl_xor(acc0.w, off, 64);
        acc1.x += __shfl_xor(acc1.x, off, 64); acc1.y += __shfl_xor(acc1.y, off, 64);
        acc1.z += __shfl_xor(acc1.z, off, 64); acc1.w += __shfl_xor(acc1.w, off, 64);
    }

    float inv0 = 1.f / s0, inv1 = 1.f / s1;

    if (out4) {
        float o0[4], o1[4];
        float a0v[4] = {acc0.x, acc0.y, acc0.z, acc0.w};
        float a1v[4] = {acc1.x, acc1.y, acc1.z, acc1.w};
        #pragma unroll
        for (int i = 0; i < 4; ++i) {
            o0[i] = a0v[i] * inv0 + bias[c0 + i];
            o1[i] = a1v[i] * inv1 + bias[64 + c0 + i];
            if (do_relu) { o0[i] = fmaxf(o0[i], 0.f); o1[i] = fmaxf(o1[i], 0.f); }
        }
        float p0 = 0.f, p1 = 0.f, p2 = 0.f, p3 = 0.f;
        #pragma unroll
        for (int i = 0; i < 4; ++i) {
            float4 w = *(const float4*)&Wout[(c0 + i) * 4];
            p0 += o0[i] * w.x; p1 += o0[i] * w.y; p2 += o0[i] * w.z; p3 += o0[i] * w.w;
        }
        #pragma unroll
        for (int i = 0; i < 4; ++i) {
            float4 w = *(const float4*)&Wout[(64 + c0 + i) * 4];
            p0 += o1[i] * w.x; p1 += o1[i] * w.y; p2 += o1[i] * w.z; p3 += o1[i] * w.w;
        }
        p0 = rowsum16(p0); p1 = rowsum16(p1);
        p2 = rowsum16(p2); p3 = rowsum16(p3);
        if (lane == 0) {
            float4 o = make_float4(p0 + bout[0], p1 + bout[1],
                                   p2 + bout[2], p3 + bout[3]);
            *(float4*)&out4[(size_t)node * 4] = o;
        }
        return;
    }

    if (g == 0) {
        float4 vb = *(const float4*)&bias[c0];
        float4 o = make_float4(acc0.x * inv0 + vb.x, acc0.y * inv0 + vb.y,
                               acc0.z * inv0 + vb.z, acc0.w * inv0 + vb.w);
        if (do_relu) {
            o.x = fmaxf(o.x, 0.f); o.y = fmaxf(o.y, 0.f);
            o.z = fmaxf(o.z, 0.f); o.w = fmaxf(o.w, 0.f);
        }
        *(float4*)&hout[(size_t)node * 128 + c0] = o;
    } else if (g == 1) {
        float4 vb = *(const float4*)&bias[64 + c0];
        float4 o = make_float4(acc1.x * inv1 + vb.x, acc1.y * inv1 + vb.y,
                               acc1.z * inv1 + vb.z, acc1.w * inv1 + vb.w);
        if (do_relu) {
            o.x = fmaxf(o.x, 0.f); o.y = fmaxf(o.y, 0.f);
            o.z = fmaxf(o.z, 0.f); o.w = fmaxf(o.w, 0.f);
        }
        *(float4*)&hout[(size_t)node * 128 + 64 + c0] = o;
    }
}

// ---------------------------------------------------------------------------
extern "C" void kernel_launch(void* const* d_in, const int* in_sizes, int n_in,
                              void* d_out, int out_size, void* d_ws,
                              size_t ws_size, hipStream_t stream) {
    // setup_inputs order:
    //  0:x 1:edge_index 2:W1l 3:b1l 4:W1r 5:b1r 6:att1 7:bias1
    //  8:W2l 9:b2l 10:W2r 11:b2r 12:att2 13:bias2
    // 14:W3l 15:b3l 16:W3r 17:b3r 18:att3 19:bias3 20:Wout 21:bout
    const float* x    = (const float*)d_in[0];
    const int*   ei   = (const int*)  d_in[1];
    const float* W1l  = (const float*)d_in[2];
    const float* b1l  = (const float*)d_in[3];
    const float* W1r  = (const float*)d_in[4];
    const float* b1r  = (const float*)d_in[5];
    const float* att1 = (const float*)d_in[6];
    const float* bias1= (const float*)d_in[7];
    const float* W2l  = (const float*)d_in[8];
    const float* b2l  = (const float*)d_in[9];
    const float* W2r  = (const float*)d_in[10];
    const float* b2r  = (const float*)d_in[11];
    const float* att2 = (const float*)d_in[12];
    const float* bias2= (const float*)d_in[13];
    const float* W3l  = (const float*)d_in[14];
    const float* b3l  = (const float*)d_in[15];
    const float* W3r  = (const float*)d_in[16];
    const float* b3r  = (const float*)d_in[17];
    const float* att3 = (const float*)d_in[18];
    const float* bias3= (const float*)d_in[19];
    const float* Wout = (const float*)d_in[20];
    const float* bout = (const float*)d_in[21];

    int N    = in_sizes[0] / DIN;
    int E    = in_sizes[1] / 2;
    int Etot = E + N;

    char* base = (char*)d_ws;
    float* h = (float*)base;              base += (size_t)N * HC * 4;
    _Float16* xlh = (_Float16*)base;      base += (size_t)N * HC * 2;
    float* xr = (float*)base;             base += (size_t)N * HC * 4;
    unsigned short* whi = (unsigned short*)base;  base += 6 * 16384 * 2;
    unsigned short* wlo = (unsigned short*)base;  base += 6 * 16384 * 2;
    int* esrc   = (int*)base;             base += (size_t)Etot * 4;
    int* rowptr = (int*)base;             base += (size_t)(((N + 1) + 3) & ~3) * 4;
    int* cursor = (int*)base;             base += (size_t)N * 4;
    int* counts = (int*)base;

    hipMemsetAsync(counts, 0, (size_t)N * sizeof(int), stream);
    hist_kernel<<<(Etot + 255) / 256, 256, 0, stream>>>(ei, E, N, counts);
    scan_kernel<<<1, 1024, 0, stream>>>(counts, rowptr, cursor, N);
    scatter_kernel<<<(Etot + 255) / 256, 256, 0, stream>>>(ei, E, N, cursor, esrc);
    prep_w<<<dim3(8, 6), 256, 0, stream>>>(W1l, W1r, W2l, W2r, W3l, W3r, whi, wlo);

    int gemm_grid = (N + 63) / 64;
    int agg_grid  = (N + 3) / 4;

    gemm_mfma_dual<<<gemm_grid, 256, 0, stream>>>(x, whi, wlo, 0, b1l, b1r, xlh, xr, N);
    gat_aggregate<<<agg_grid, 256, 0, stream>>>(xlh, xr, rowptr, esrc, att1, bias1,
                                                h, N, 1, nullptr, nullptr, nullptr);
    gemm_mfma_dual<<<gemm_grid, 256, 0, stream>>>(h, whi, wlo, 2, b2l, b2r, xlh, xr, N);
    gat_aggregate<<<agg_grid, 256, 0, stream>>>(xlh, xr, rowptr, esrc, att2, bias2,
                                                h, N, 1, nullptr, nullptr, nullptr);
    gemm_mfma_dual<<<gemm_grid, 256, 0, stream>>>(h, whi, wlo, 4, b3l, b3r, xlh, xr, N);
    // layer 3: fused relu + output projection, h never materialized
    gat_aggregate<<<agg_grid, 256, 0, stream>>>(xlh, xr, rowptr, esrc, att3, bias3,
                                                nullptr, N, 1, Wout, bout,
                                                (float*)d_out);
}